// Round 5
// baseline (567.421 us; speedup 1.0000x reference)
//
#include <hip/hip_runtime.h>

#define NS 100000

typedef _Float16 half8v __attribute__((ext_vector_type(8)));
typedef _Float16 half4v __attribute__((ext_vector_type(4)));
typedef _Float16 half2v __attribute__((ext_vector_type(2)));
typedef float    f32x16 __attribute__((ext_vector_type(16)));
typedef unsigned int uint2v __attribute__((ext_vector_type(2)));

// ============================================================================
// Kernel 1: build Q per component (fp32, LDS), expm via scaling+squaring
// Taylor (terms to k=6, ||A||1 <= 0.25 -> remainder < 2e-8), then
// P^{1,2,3,4} + pi-folded P1. 4x4 register-tiled fp32 matmuls.
// Store f16: Pw[m][v][64][64].
// ============================================================================
__device__ __forceinline__ float wave_sum64(float v) {
#pragma unroll
  for (int off = 32; off > 0; off >>= 1) v += __shfl_xor(v, off, 64);
  return v;
}
__device__ __forceinline__ float wave_max64(float v) {
#pragma unroll
  for (int off = 32; off > 0; off >>= 1) v = fmaxf(v, __shfl_xor(v, off, 64));
  return v;
}

__device__ __forceinline__ void mm64(const float* __restrict__ Lt,
                                     const float* __restrict__ Rn,
                                     int ro, int co, float r[16]) {
#pragma unroll 4
  for (int kk0 = 0; kk0 < 64; kk0 += 4) {
    float4 tv[4], av[4];
#pragma unroll
    for (int j = 0; j < 4; ++j) {
      tv[j] = *(const float4*)(Lt + (kk0 + j) * 64 + ro);
      av[j] = *(const float4*)(Rn + (kk0 + j) * 64 + co);
    }
#pragma unroll
    for (int j = 0; j < 4; ++j) {
      const float* tp = (const float*)&tv[j];
      const float* ap = (const float*)&av[j];
#pragma unroll
      for (int i = 0; i < 4; ++i)
#pragma unroll
        for (int c = 0; c < 4; ++c) r[i * 4 + c] += tp[i] * ap[c];
    }
  }
}

__global__ __launch_bounds__(256) void prep_P(const float* __restrict__ rates,
                                              const float* __restrict__ pi_inv,
                                              _Float16* __restrict__ Pw) {
  __shared__ __align__(16) float Ab[4096];
  __shared__ __align__(16) float Tt[4096];
  __shared__ __align__(16) float Sb[4096];
  __shared__ float pi_l[64];
  __shared__ float sc_sh[2];
  const int t = threadIdx.x;
  const int m = blockIdx.x;

  if (t < 64) {
    float y = (t < 63) ? pi_inv[m * 63 + t] : 0.f;
    float ns = wave_sum64(y * y);
    float ps = (t < 63) ? (2.f * y / (ns + 1.f)) : ((ns - 1.f) / (ns + 1.f));
    pi_l[t] = ps * ps;
  }
  __syncthreads();

  for (int it = 0; it < 16; ++it) {
    int e = t + 256 * it, i = e >> 6, j = e & 63;
    float v = 0.f;
    if (i != j) {
      int ii = i < j ? i : j, jj = i < j ? j : i;
      int tri = ii * 63 - (ii * (ii - 1)) / 2 + (jj - ii - 1);
      float r = rates[m * 2016 + tri];
      v = r * r * pi_l[j];
    }
    Ab[e] = v;
  }
  __syncthreads();
  if (t < 64) {
    float s = 0.f;
    for (int j = 0; j < 64; ++j) s += Ab[t * 64 + ((j + t) & 63)];
    Ab[t * 64 + t] = -s;
    float em = wave_sum64(pi_l[t] * s);
    if (t == 0) sc_sh[0] = 0.05f / em;
  }
  __syncthreads();
  const float sc0 = sc_sh[0];
  if (t < 64) {
    float s = 0.f;
    for (int i = 0; i < 64; ++i) s += fabsf(Ab[i * 64 + t]);
    float n1 = wave_max64(s * fabsf(sc0));
    if (t == 0) {
      int sq = 0;
      while (n1 > 0.25f && sq < 24) { n1 *= 0.5f; ++sq; }
      sc_sh[0] = ldexpf(sc0, -sq);
      sc_sh[1] = (float)sq;
    }
  }
  __syncthreads();
  const float scl = sc_sh[0];
  const int   sq  = (int)sc_sh[1];
  for (int it = 0; it < 16; ++it) {
    int e = t + 256 * it, i = e >> 6, j = e & 63;
    float a = Ab[e] * scl;
    Ab[e] = a;
    Tt[j * 64 + i] = a;
  }
  __syncthreads();

  const int ro = (t >> 4) * 4, co = (t & 15) * 4;
  float ss[16];
#pragma unroll
  for (int i = 0; i < 16; ++i) ss[i] = 0.f;

  for (int k = 2; k <= 6; ++k) {
    float r[16];
#pragma unroll
    for (int i = 0; i < 16; ++i) r[i] = 0.f;
    mm64(Tt, Ab, ro, co, r);
    __syncthreads();
    float inv = 1.f / (float)k;
#pragma unroll
    for (int i = 0; i < 16; ++i) { r[i] *= inv; ss[i] += r[i]; }
#pragma unroll
    for (int j = 0; j < 4; ++j) {
      float4 w = {r[0 * 4 + j], r[1 * 4 + j], r[2 * 4 + j], r[3 * 4 + j]};
      *(float4*)(Tt + (co + j) * 64 + ro) = w;
    }
    __syncthreads();
  }

  float s[16];
#pragma unroll
  for (int i = 0; i < 4; ++i)
#pragma unroll
    for (int j = 0; j < 4; ++j)
      s[i * 4 + j] = ss[i * 4 + j] + Ab[(ro + i) * 64 + co + j] +
                     (((ro + i) == (co + j)) ? 1.f : 0.f);
  __syncthreads();
#pragma unroll
  for (int i = 0; i < 4; ++i) {
    float4 w = {s[i * 4 + 0], s[i * 4 + 1], s[i * 4 + 2], s[i * 4 + 3]};
    *(float4*)(Sb + (ro + i) * 64 + co) = w;
  }
#pragma unroll
  for (int j = 0; j < 4; ++j) {
    float4 w = {s[0 * 4 + j], s[1 * 4 + j], s[2 * 4 + j], s[3 * 4 + j]};
    *(float4*)(Tt + (co + j) * 64 + ro) = w;
  }
  __syncthreads();

  for (int q = 0; q < sq; ++q) {
    float r[16];
#pragma unroll
    for (int i = 0; i < 16; ++i) r[i] = 0.f;
    mm64(Tt, Sb, ro, co, r);
    __syncthreads();
#pragma unroll
    for (int i = 0; i < 16; ++i) s[i] = r[i];
#pragma unroll
    for (int i = 0; i < 4; ++i) {
      float4 w = {s[i * 4 + 0], s[i * 4 + 1], s[i * 4 + 2], s[i * 4 + 3]};
      *(float4*)(Sb + (ro + i) * 64 + co) = w;
    }
#pragma unroll
    for (int j = 0; j < 4; ++j) {
      float4 w = {s[0 * 4 + j], s[1 * 4 + j], s[2 * 4 + j], s[3 * 4 + j]};
      *(float4*)(Tt + (co + j) * 64 + ro) = w;
    }
    __syncthreads();
  }

  _Float16* base = Pw + (size_t)m * 5 * 4096;
#pragma unroll
  for (int i = 0; i < 4; ++i) {
    half4v h1, h4;
#pragma unroll
    for (int j = 0; j < 4; ++j) {
      float v = s[i * 4 + j];
      h1[j] = (_Float16)v;
      h4[j] = (_Float16)(pi_l[ro + i] * v);
    }
    *(half4v*)(base + (ro + i) * 64 + co)            = h1;
    *(half4v*)(base + 4 * 4096 + (ro + i) * 64 + co) = h4;
  }
  float p2[16];
#pragma unroll
  for (int i = 0; i < 16; ++i) p2[i] = 0.f;
  mm64(Tt, Sb, ro, co, p2);
  __syncthreads();
#pragma unroll
  for (int i = 0; i < 4; ++i) {
    float4 w = {p2[i * 4 + 0], p2[i * 4 + 1], p2[i * 4 + 2], p2[i * 4 + 3]};
    *(float4*)(Ab + (ro + i) * 64 + co) = w;
    half4v h;
#pragma unroll
    for (int j = 0; j < 4; ++j) h[j] = (_Float16)p2[i * 4 + j];
    *(half4v*)(base + 1 * 4096 + (ro + i) * 64 + co) = h;
  }
#pragma unroll
  for (int j = 0; j < 4; ++j) {
    float4 w = {p2[0 * 4 + j], p2[1 * 4 + j], p2[2 * 4 + j], p2[3 * 4 + j]};
    *(float4*)(Tt + (co + j) * 64 + ro) = w;
  }
  __syncthreads();
  {
    float r3[16], r4[16];
#pragma unroll
    for (int i = 0; i < 16; ++i) { r3[i] = 0.f; r4[i] = 0.f; }
#pragma unroll 2
    for (int kk0 = 0; kk0 < 64; kk0 += 4) {
      float4 tv[4], a3[4], a4[4];
#pragma unroll
      for (int j = 0; j < 4; ++j) {
        tv[j] = *(const float4*)(Tt + (kk0 + j) * 64 + ro);
        a3[j] = *(const float4*)(Sb + (kk0 + j) * 64 + co);
        a4[j] = *(const float4*)(Ab + (kk0 + j) * 64 + co);
      }
#pragma unroll
      for (int j = 0; j < 4; ++j) {
        const float* tp = (const float*)&tv[j];
        const float* p3 = (const float*)&a3[j];
        const float* p4 = (const float*)&a4[j];
#pragma unroll
        for (int i = 0; i < 4; ++i)
#pragma unroll
          for (int c = 0; c < 4; ++c) {
            r3[i * 4 + c] += tp[i] * p3[c];
            r4[i * 4 + c] += tp[i] * p4[c];
          }
      }
    }
#pragma unroll
    for (int i = 0; i < 4; ++i) {
      half4v h3, h4;
#pragma unroll
      for (int j = 0; j < 4; ++j) {
        h3[j] = (_Float16)r3[i * 4 + j];
        h4[j] = (_Float16)r4[i * 4 + j];
      }
      *(half4v*)(base + 2 * 4096 + (ro + i) * 64 + co) = h3;
      *(half4v*)(base + 3 * 4096 + (ro + i) * 64 + co) = h4;
    }
  }
}

// ============================================================================
// Kernel 2: fused pruning. Block = 256 thr (4 waves), 64 sites in 64KB LDS.
// Wave w: site-group (w>>1), components m = (w&1)*4 .. +3 (block-synchronized
// m trajectories -> waves sharing m hit L1 on each other's P-fragment lines).
// Version-grouped message order: 10 pf-loads per m (leaf pairs share).
// Messages processed one row-half at a time: pf-half(16)+acc(16) transient,
// peak arch-VGPR liveness ~120 -> no scratch spill at the 128-reg split.
// ============================================================================
struct Pk { half2v h[16]; };  // h[hh*8+p] = rows of half hh (RTE-packed)

__device__ __forceinline__ void swap32(unsigned& a, unsigned& b) {
#if __has_builtin(__builtin_amdgcn_permlane32_swap)
  uint2v r = __builtin_amdgcn_permlane32_swap(a, b, false, false);
  a = r.x; b = r.y;
#else
  unsigned pa = (unsigned)__shfl_xor((int)a, 32, 64);
  unsigned pb = (unsigned)__shfl_xor((int)b, 32, 64);
  bool hi = (threadIdx.x & 32) != 0;
  unsigned na = hi ? pb : a;
  unsigned nb = hi ? b : pa;
  a = na; b = nb;
#endif
}

__device__ __forceinline__ half8v bfrag_state(const Pk& s, int kt) {
  const int rt = kt >> 1, b = (kt & 1) * 4;
  unsigned a0 = __builtin_bit_cast(unsigned, s.h[rt * 8 + b + 0]);
  unsigned c0 = __builtin_bit_cast(unsigned, s.h[rt * 8 + b + 2]);
  unsigned a1 = __builtin_bit_cast(unsigned, s.h[rt * 8 + b + 1]);
  unsigned c1 = __builtin_bit_cast(unsigned, s.h[rt * 8 + b + 3]);
  swap32(a0, c0);
  swap32(a1, c1);
  union { half8v v; unsigned u[4]; } U;
  U.u[0] = a0; U.u[1] = a1; U.u[2] = c0; U.u[3] = c1;
  return U.v;
}

__device__ __forceinline__ void zero16(f32x16& a) {
#pragma unroll
  for (int i = 0; i < 16; ++i) a[i] = 0.f;
}

__device__ __forceinline__ half2v pk2(float x, float y) {
  half2v h; h.x = (_Float16)x; h.y = (_Float16)y; return h;  // RTE
}

__device__ __forceinline__ half8v ld_bf(const _Float16* __restrict__ xg,
                                        int leaf, int kt, int s31, int hb, int sw) {
  return *(const half8v*)(xg + s31 * 512 + ((leaf * 64 + kt * 16 + hb * 8) ^ sw));
}

// A,B overwritten: A = A_in * (P@X_la), B = B_in * (P@X_lb)   (mul==true)
//               or A =        P@X_la,  B =        P@X_lb      (mul==false)
template <bool MUL>
__device__ __forceinline__ void leaf_pair(const _Float16* __restrict__ Pv,
                                          const _Float16* __restrict__ xg,
                                          int la, int lb, int s31, int hb, int sw,
                                          Pk& A, Pk& B) {
#pragma unroll
  for (int hh = 0; hh < 2; ++hh) {
    half8v pf[4];
#pragma unroll
    for (int kt = 0; kt < 4; ++kt)
      pf[kt] = *(const half8v*)(Pv + ((hh * 32 + s31) * 64 + kt * 16 + hb * 8));
    {
      f32x16 a; zero16(a);
#pragma unroll
      for (int kt = 0; kt < 4; ++kt)
        a = __builtin_amdgcn_mfma_f32_32x32x16_f16(pf[kt], ld_bf(xg, la, kt, s31, hb, sw), a, 0, 0, 0);
#pragma unroll
      for (int p = 0; p < 8; ++p) {
        half2v v = pk2(a[2 * p], a[2 * p + 1]);
        A.h[hh * 8 + p] = MUL ? (half2v)(A.h[hh * 8 + p] * v) : v;
      }
    }
    {
      f32x16 b; zero16(b);
#pragma unroll
      for (int kt = 0; kt < 4; ++kt)
        b = __builtin_amdgcn_mfma_f32_32x32x16_f16(pf[kt], ld_bf(xg, lb, kt, s31, hb, sw), b, 0, 0, 0);
#pragma unroll
      for (int p = 0; p < 8; ++p) {
        half2v v = pk2(b[2 * p], b[2 * p + 1]);
        B.h[hh * 8 + p] = MUL ? (half2v)(B.h[hh * 8 + p] * v) : v;
      }
    }
  }
}

__device__ __forceinline__ Pk state_msg(const _Float16* __restrict__ Pv,
                                        const Pk& src, int s31, int hb) {
  Pk o;
#pragma unroll
  for (int hh = 0; hh < 2; ++hh) {
    half8v pf[4];
#pragma unroll
    for (int kt = 0; kt < 4; ++kt)
      pf[kt] = *(const half8v*)(Pv + ((hh * 32 + s31) * 64 + kt * 16 + hb * 8));
    f32x16 a; zero16(a);
#pragma unroll
    for (int kt = 0; kt < 4; ++kt)
      a = __builtin_amdgcn_mfma_f32_32x32x16_f16(pf[kt], bfrag_state(src, kt), a, 0, 0, 0);
#pragma unroll
    for (int p = 0; p < 8; ++p) o.h[hh * 8 + p] = pk2(a[2 * p], a[2 * p + 1]);
  }
  return o;
}

__device__ __forceinline__ float root_dot(const _Float16* __restrict__ Pv,
                                          const Pk& s13, const Pk& m12,
                                          int s31, int hb) {
  float part = 0.f;
#pragma unroll
  for (int hh = 0; hh < 2; ++hh) {
    half8v pf[4];
#pragma unroll
    for (int kt = 0; kt < 4; ++kt)
      pf[kt] = *(const half8v*)(Pv + ((hh * 32 + s31) * 64 + kt * 16 + hb * 8));
    f32x16 a; zero16(a);
#pragma unroll
    for (int kt = 0; kt < 4; ++kt)
      a = __builtin_amdgcn_mfma_f32_32x32x16_f16(pf[kt], bfrag_state(s13, kt), a, 0, 0, 0);
#pragma unroll
    for (int p = 0; p < 8; ++p)
      part += (float)m12.h[hh * 8 + p].x * a[2 * p]
            + (float)m12.h[hh * 8 + p].y * a[2 * p + 1];
  }
  return part;
}

__device__ __forceinline__ Pk mulpk(const Pk& a, const Pk& b) {
  Pk o;
#pragma unroll
  for (int i = 0; i < 16; ++i) o.h[i] = a.h[i] * b.h[i];
  return o;
}

__global__ __launch_bounds__(256, 2) void tree_fwd(const float* __restrict__ X,
                                                   const _Float16* __restrict__ Pw,
                                                   float* __restrict__ out) {
  __shared__ __align__(16) _Float16 xs[64 * 512];  // 64 sites x 1KB f16, swizzled
  const int t = threadIdx.x;
  const int sb0 = blockIdx.x * 64;
  const int nsv = (NS - sb0) < 64 ? (NS - sb0) : 64;

  // ---- stage X (fp32, coalesced) -> f16 LDS, XOR-swizzle bits 3..5 ----
  for (int it = 0; it < 32; ++it) {
    int e0 = (t + 256 * it) * 4;
    int site = e0 >> 9;
    int k = e0 & 511;
    float4 v = {0.f, 0.f, 0.f, 0.f};
    if (site < nsv) v = ((const float4*)X)[(size_t)(sb0 + site) * 128 + (k >> 2)];
    half4v h;
    h.x = (_Float16)v.x; h.y = (_Float16)v.y; h.z = (_Float16)v.z; h.w = (_Float16)v.w;
    *(half4v*)(xs + site * 512 + (k ^ ((site & 7) << 3))) = h;
  }
  __syncthreads();

  const int lane = t & 63, wav = t >> 6;
  const int s31 = lane & 31, hb = lane >> 5;
  const int sw = (s31 & 7) << 3;
  const int grp = wav >> 1;                 // site group 0/1
  const int mbase = (wav & 1) * 4;          // component half
  const _Float16* xg = xs + grp * 32 * 512;
  const int siteG = sb0 + grp * 32 + s31;

#pragma unroll 1
  for (int mi = 0; mi < 4; ++mi) {
    const int m = mbase + mi;
    const _Float16* Pm = Pw + (size_t)m * 5 * 4096;
    const _Float16* v0 = Pm;
    const _Float16* v1 = Pm + 4096;
    const _Float16* v2 = Pm + 2 * 4096;
    const _Float16* v3 = Pm + 3 * 4096;
    const _Float16* v4 = Pm + 4 * 4096;

    Pk A, B, C, D;
    leaf_pair<false>(v0, xg, 0, 4, s31, hb, sw, A, B);  // A=msg(l0), B=msg(l4)
    leaf_pair<true >(v1, xg, 1, 5, s31, hb, sw, A, B);  // A=s8, B=s10
    leaf_pair<false>(v2, xg, 2, 6, s31, hb, sw, C, D);  // C=msg(l2), D=msg(l6)
    leaf_pair<true >(v3, xg, 3, 7, s31, hb, sw, C, D);  // C=s9, D=s11
    Pk m8  = state_msg(v0, A, s31, hb);                 // A dead
    Pk s12 = mulpk(m8, state_msg(v1, C, s31, hb));      // C dead
    Pk m10 = state_msg(v2, B, s31, hb);                 // B dead
    Pk s13 = mulpk(m10, state_msg(v3, D, s31, hb));     // D dead
    Pk m12 = state_msg(v4, s12, s31, hb);               // pi-folded P1
    float part = root_dot(v1, s13, m12, s31, hb);
    part += __shfl_xor(part, 32, 64);
    if (lane < 32 && siteG < NS) out[(size_t)siteG * 8 + m] = part;
  }
}

extern "C" void kernel_launch(void* const* d_in, const int* in_sizes, int n_in,
                              void* d_out, int out_size, void* d_ws, size_t ws_size,
                              hipStream_t stream) {
  const float* X      = (const float*)d_in[0];
  const float* rates  = (const float*)d_in[1];
  const float* pi_inv = (const float*)d_in[2];
  _Float16* Pw = (_Float16*)d_ws;   // 8 * 5 * 4096 * 2B = 320 KiB

  prep_P<<<8, 256, 0, stream>>>(rates, pi_inv, Pw);
  tree_fwd<<<(NS + 63) / 64, 256, 0, stream>>>(X, Pw, (float*)d_out);
}